// Round 3
// baseline (721.925 us; speedup 1.0000x reference)
//
#include <hip/hip_runtime.h>
#include <math.h>

// GaussianScaleReadout: y[b,o] = sum_k alpha[b,k] * (sum_c h[b,c,k]*w[k,o,c] + bias[k,o])
//
// Thread-per-query design: each thread owns one query b, streams its 4 KiB of h
// sequentially (element j = c*8+k, k fastest: float4 i -> k=(i&1)*4+e, c=i>>1),
// accumulates 3 outputs in registers -- NO cross-lane reduction at all, softmax
// computed once per query. Weights (12 KiB) live in LDS, permuted to
// W2[i][e][o] = w[k(i,e)][o][c(i)] so each loop step reads 12 contiguous floats
// at a wave-uniform address (pure LDS broadcast, 3x ds_read_b128, no conflicts).
// Per-lane streaming keeps full cache-line utilization (each lane's 64B line is
// consumed by 4 consecutive dwordx4); 1-chunk-deep register pipeline keeps
// 8 KiB/wave in flight -> 64 KiB/CU at 8 waves/CU, well above the ~9 KiB
// Little's-law requirement for this CU's HBM share.

#define C_H   128
#define KSC   8
#define QBLK  256

__global__ __launch_bounds__(QBLK)
void gsr_kernel(const float* __restrict__ h,      // [BQ, C_H, K]
                const float* __restrict__ cell,   // [BQ, 2]
                const float* __restrict__ w,      // [K, 3, C_H]
                const float* __restrict__ bias,   // [K, 3]
                float* __restrict__ out,          // [BQ, 3]
                int bq)
{
    __shared__ float W2[256 * 12];   // [i=c*2+kh][e][o]
    __shared__ float B2[24];         // bias[k][o]

    const int t = threadIdx.x;

    // ---- cooperative weight permute into LDS (once per block) ----
    {
        const int i  = t;            // 256 threads -> one i-slot (12 floats) each
        const int kh = i & 1;
        const int c  = i >> 1;
        #pragma unroll
        for (int e = 0; e < 4; ++e)
            #pragma unroll
            for (int o = 0; o < 3; ++o)
                W2[i * 12 + e * 3 + o] = w[(kh * 4 + e) * (3 * C_H) + o * C_H + c];
        if (t < 24) B2[t] = bias[t];
    }
    __syncthreads();

    const int b = blockIdx.x * QBLK + t;
    if (b >= bq) return;

    // ---- tau + alpha (once per query) ----
    const float inv_two_sigma_sq = 0.78125f;             // 1 / (2*0.8^2)
    const float log_2_over_inp   = -4.8520302639196171f; // log(2/256)
    const float seven_over_log30 = 2.0580814087539097f;  // 7 / log(30)

    const float2 cg = ((const float2*)cell)[b];
    const float geo = fmaxf(sqrtf(cg.x * cg.y), 1e-10f);
    const float log_s = log_2_over_inp - __logf(geo);
    float tau = seven_over_log30 * log_s;
    tau = fminf(fmaxf(tau, 0.0f), 7.0f);

    float al[8], s = 0.0f;
    #pragma unroll
    for (int k = 0; k < 8; ++k) {
        const float d = (float)k - tau;
        al[k] = __expf(-d * d * inv_two_sigma_sq);
        s += al[k];
    }
    const float inv = 1.0f / s;
    #pragma unroll
    for (int k = 0; k < 8; ++k) al[k] *= inv;

    // ---- accumulator init with bias ----
    float acc[3];
    #pragma unroll
    for (int o = 0; o < 3; ++o) {
        float a0 = 0.0f;
        #pragma unroll
        for (int k = 0; k < 8; ++k)
            a0 = fmaf(al[k], B2[k * 3 + o], a0);
        acc[o] = a0;
    }

    // ---- stream this query's 4 KiB, 128 B chunks, 1-chunk prefetch pipeline ----
    const float4* hp = (const float4*)(h + (size_t)b * (C_H * KSC));
    float4 cur[8], nxt[8];
    #pragma unroll
    for (int u = 0; u < 8; ++u) cur[u] = hp[u];

    for (int ch = 0; ch < 32; ++ch) {
        if (ch < 31) {
            #pragma unroll
            for (int u = 0; u < 8; ++u) nxt[u] = hp[(ch + 1) * 8 + u];
        }
        const int ibase = ch * 8;
        #pragma unroll
        for (int u = 0; u < 8; ++u) {
            const int kh = u & 1;                 // (ibase+u)&1, ibase even
            const float* wrow = &W2[(ibase + u) * 12];
            const float he[4] = {cur[u].x, cur[u].y, cur[u].z, cur[u].w};
            #pragma unroll
            for (int e = 0; e < 4; ++e) {
                const float ha = he[e] * al[kh * 4 + e];
                #pragma unroll
                for (int o = 0; o < 3; ++o)
                    acc[o] = fmaf(ha, wrow[e * 3 + o], acc[o]);
            }
        }
        if (ch < 31) {
            #pragma unroll
            for (int u = 0; u < 8; ++u) cur[u] = nxt[u];
        }
    }

    // ---- store 3 floats (wave stores coalesce into contiguous 768 B) ----
    out[(size_t)b * 3 + 0] = acc[0];
    out[(size_t)b * 3 + 1] = acc[1];
    out[(size_t)b * 3 + 2] = acc[2];
}

extern "C" void kernel_launch(void* const* d_in, const int* in_sizes, int n_in,
                              void* d_out, int out_size, void* d_ws, size_t ws_size,
                              hipStream_t stream) {
    const float* h    = (const float*)d_in[0];
    const float* cell = (const float*)d_in[1];
    const float* w    = (const float*)d_in[2];
    const float* bias = (const float*)d_in[3];
    float* out = (float*)d_out;
    const int bq = in_sizes[0] / (C_H * KSC);

    const int nblocks = (bq + QBLK - 1) / QBLK;   // 512 for BQ=131072
    gsr_kernel<<<nblocks, QBLK, 0, stream>>>(h, cell, w, bias, out, bq);
}

// Round 4
// 707.089 us; speedup vs baseline: 1.0210x; 1.0210x over previous
//
#include <hip/hip_runtime.h>
#include <math.h>

// GaussianScaleReadout: y[b,o] = sum_k alpha[b,k] * (sum_c h[b,c,k]*w[k,o,c] + bias[k,o])
// Memory-bound on h (512 MiB, read exactly once). One wave handles 4 queries per
// iteration: 16 KiB contiguous -> 16 coalesced dwordx4 wave-loads (each 1 KiB,
// 16 cache lines). Softmax under the load shadow; 12 independent shuffle-
// reduction chains. R4 tweak: software-pipelined grid-stride loop -- the next
// group's 16 loads are issued BEFORE the ~720-cycle reduction phase (hv regs
// are dead after the FMA block, so no extra VGPR pressure).
//
// Index algebra (h inner layout [c,k], k fastest; float4 j = i*64+lane of the
// 4-query block): g = i>>2 (query), k = (lane&1)*4+e, c = (i&3)*32+(lane>>1).
// Weights (12 KiB) live in 48 VGPRs per lane, loaded once per wave.

#define C_H   128
#define KSC   8

constexpr int NBLOCKS  = 2048;   // grid-stride, 4 iters/wave at BQ=131072
constexpr int NTHREADS = 256;    // 4 waves/block
constexpr int NWAVES   = NBLOCKS * NTHREADS / 64;  // 8192

__global__ __launch_bounds__(NTHREADS)
void gsr_kernel(const float* __restrict__ h,      // [BQ, C_H, K]
                const float* __restrict__ cell,   // [BQ, 2]
                const float* __restrict__ w,      // [K, 3, C_H]
                const float* __restrict__ bias,   // [K, 3]
                float* __restrict__ out,          // [BQ, 3]
                int bq)
{
    const int lane   = threadIdx.x & 63;
    const int waveId = blockIdx.x * (NTHREADS / 64) + (threadIdx.x >> 6);

    // ---- one-time per-wave weight preload into registers ----
    const int kbase = (lane & 1) * 4;   // this lane's k-subset base (0 or 4)
    const int chalf = lane >> 1;
    float wreg[4][4][3];                // [i&3][e][o]
    #pragma unroll
    for (int i4 = 0; i4 < 4; ++i4) {
        #pragma unroll
        for (int e = 0; e < 4; ++e) {
            const int k = kbase + e;
            const int c = i4 * 32 + chalf;
            #pragma unroll
            for (int o = 0; o < 3; ++o)
                wreg[i4][e][o] = w[k * (3*C_H) + o * C_H + c];
        }
    }
    // bias fragments: lane 0 covers k=0..3, lane 1 covers k=4..7, others zero;
    // the cross-lane reduction sums them exactly once.
    float breg[4][3];
    #pragma unroll
    for (int e = 0; e < 4; ++e)
        #pragma unroll
        for (int o = 0; o < 3; ++o)
            breg[e][o] = (lane < 2) ? bias[(kbase + e) * 3 + o] : 0.0f;

    const float inv_two_sigma_sq = 0.78125f;             // 1 / (2*0.8^2)
    const float log_2_over_inp   = -4.8520302639196171f; // log(2/256)
    const float seven_over_log30 = 2.0580814087539097f;  // 7 / log(30)

    const int ngrp = bq >> 2;            // groups of 4 queries
    const float2* cell2 = (const float2*)cell;

    int grp = waveId;
    if (grp >= ngrp) return;

    // ---- preheader: load first group's h (16 KiB contiguous, coalesced) ----
    float4 hv[16];
    {
        const float4* hp = (const float4*)(h + (size_t)(grp << 2) * (C_H * KSC));
        #pragma unroll
        for (int i = 0; i < 16; ++i)
            hv[i] = hp[i * 64 + lane];
    }

    for (; grp < ngrp; grp += NWAVES) {
        const int b4 = grp << 2;

        // ---- tau + alpha for the 4 queries (under load shadow) ----
        float al[4][4];   // [g][e]: alpha for k = kbase+e
        float acc[4][3];
        #pragma unroll
        for (int g = 0; g < 4; ++g) {
            const float2 cg = cell2[b4 + g];
            const float geo = fmaxf(sqrtf(cg.x * cg.y), 1e-10f);
            const float log_s = log_2_over_inp - __logf(geo);
            float tau = seven_over_log30 * log_s;
            tau = fminf(fmaxf(tau, 0.0f), 7.0f);

            float ek[8], s = 0.0f;
            #pragma unroll
            for (int k = 0; k < 8; ++k) {
                const float d = (float)k - tau;
                ek[k] = __expf(-d * d * inv_two_sigma_sq);
                s += ek[k];
            }
            const float inv = 1.0f / s;
            #pragma unroll
            for (int e = 0; e < 4; ++e)
                al[g][e] = ((lane & 1) ? ek[4 + e] : ek[e]) * inv;

            // bias into accumulator init (zero except lanes 0/1)
            #pragma unroll
            for (int o = 0; o < 3; ++o) {
                acc[g][o] = al[g][0] * breg[0][o];
                #pragma unroll
                for (int e = 1; e < 4; ++e)
                    acc[g][o] = fmaf(al[g][e], breg[e][o], acc[g][o]);
            }
        }

        // ---- FMA block: consumes hv (last use of the loads) ----
        #pragma unroll
        for (int i = 0; i < 16; ++i) {
            const int g  = i >> 2;
            const int i4 = i & 3;
            const float he[4] = {hv[i].x, hv[i].y, hv[i].z, hv[i].w};
            #pragma unroll
            for (int e = 0; e < 4; ++e) {
                const float ha = he[e] * al[g][e];
                #pragma unroll
                for (int o = 0; o < 3; ++o)
                    acc[g][o] = fmaf(ha, wreg[i4][e][o], acc[g][o]);
            }
        }

        // ---- prefetch next group's h BEFORE the reduction (hv is dead) ----
        const int ngx = grp + NWAVES;
        if (ngx < ngrp) {
            const float4* hp = (const float4*)(h + (size_t)(ngx << 2) * (C_H * KSC));
            #pragma unroll
            for (int i = 0; i < 16; ++i)
                hv[i] = hp[i * 64 + lane];
        }

        // ---- 12 independent butterfly reductions over 64 lanes ----
        #pragma unroll
        for (int off = 32; off > 0; off >>= 1) {
            #pragma unroll
            for (int g = 0; g < 4; ++g) {
                acc[g][0] += __shfl_xor(acc[g][0], off, 64);
                acc[g][1] += __shfl_xor(acc[g][1], off, 64);
                acc[g][2] += __shfl_xor(acc[g][2], off, 64);
            }
        }

        // ---- lane 0 stores 12 contiguous floats as 3 x float4 ----
        if (lane == 0) {
            float4* op = (float4*)(out + (size_t)b4 * 3);
            op[0] = make_float4(acc[0][0], acc[0][1], acc[0][2], acc[1][0]);
            op[1] = make_float4(acc[1][1], acc[1][2], acc[2][0], acc[2][1]);
            op[2] = make_float4(acc[2][2], acc[3][0], acc[3][1], acc[3][2]);
        }
    }
}

extern "C" void kernel_launch(void* const* d_in, const int* in_sizes, int n_in,
                              void* d_out, int out_size, void* d_ws, size_t ws_size,
                              hipStream_t stream) {
    const float* h    = (const float*)d_in[0];
    const float* cell = (const float*)d_in[1];
    const float* w    = (const float*)d_in[2];
    const float* bias = (const float*)d_in[3];
    float* out = (float*)d_out;
    const int bq = in_sizes[0] / (C_H * KSC);

    gsr_kernel<<<NBLOCKS, NTHREADS, 0, stream>>>(h, cell, w, bias, out, bq);
}